// Round 4
// baseline (1054.406 us; speedup 1.0000x reference)
//
#include <hip/hip_runtime.h>
#include <hip/hip_bf16.h>

#define T_STEPS 512
#define BATCH   4096
#define OBS     64
#define ACT     16
#define HDIM    64
#define ROWS    8     // batch rows per block (512 blocks -> 2 blocks/CU -> 2 waves/SIMD)

typedef short s8v __attribute__((ext_vector_type(8)));   // 8 bf16 (4 VGPR) MFMA A/B frag
typedef float f4v __attribute__((ext_vector_type(4)));   // MFMA C/D frag

__device__ __forceinline__ unsigned short f2bf(float f) {
    unsigned u = __builtin_bit_cast(unsigned, f);
    u += 0x7FFFu + ((u >> 16) & 1u);
    return (unsigned short)(u >> 16);
}
__device__ __forceinline__ float bf2f(unsigned short b) {
    return __builtin_bit_cast(float, ((unsigned)b) << 16);
}
__device__ __forceinline__ float ftanh(float x) {
    float ax = fabsf(x);
    float e  = __expf(2.0f * ax);
    float r  = 1.0f - 2.0f * __builtin_amdgcn_rcpf(e + 1.0f);
    return copysignf(r, x);
}
// split 8 f32 -> bf16 hi frag + bf16 lo (residual) frag
__device__ __forceinline__ void split8(float4 A, float4 B, s8v& hi, s8v& lo) {
    float v[8] = {A.x, A.y, A.z, A.w, B.x, B.y, B.z, B.w};
    #pragma unroll
    for (int i = 0; i < 8; ++i) {
        unsigned short h = f2bf(v[i]);
        hi[i] = (short)h;
        lo[i] = (short)f2bf(v[i] - bf2f(h));
    }
}

// raw barrier: drain LDS only; global loads/stores stay in flight across it
#define BAR() do { \
    asm volatile("s_waitcnt lgkmcnt(0)" ::: "memory"); \
    __builtin_amdgcn_s_barrier(); \
    asm volatile("" ::: "memory"); \
} while (0)

#define MFMA16(A, B, C) __builtin_amdgcn_mfma_f32_16x16x32_bf16((A), (B), (C), 0, 0, 0)

// Fused: per step, recurrence layers for t AND capture (z1) layers for t+1 share
// the two block barriers. z1 stays in registers (capture L2 D-layout == blend layout).
__global__ __launch_bounds__(256, 2) void fused_cell(
    const float* __restrict__ x,  const float* __restrict__ h0,
    const float* __restrict__ g,  const float* __restrict__ a,
    const float* __restrict__ Wc1, const float* __restrict__ bc1,
    const float* __restrict__ Wc2, const float* __restrict__ bc2,
    const float* __restrict__ Wp1, const float* __restrict__ bp1,
    const float* __restrict__ Wp2, const float* __restrict__ bp2,
    float* __restrict__ outs, float* __restrict__ hfin, float* __restrict__ capt)
{
    __shared__ short ha [16 * 168];  // [h_hi 0..63 | h_lo 64..127 | a_hi 128..143 | a_lo 144..159]
    __shared__ short t1s[16 * 152];  // recur t1:  [hi 0..63 | lo 64..127]
    __shared__ short t1c[16 * 152];  // capture t1 (for t+1), same layout

    const int tid  = threadIdx.x;
    const int l    = tid & 63;
    const int w    = tid >> 6;
    const int c    = l & 15;            // A-frag row / D col (within 16-col group)
    const int q    = l >> 4;            // k-group; D row-group
    const int n    = (w << 4) | c;      // output channel
    const int rgrp = q << 2;            // D rows rgrp..rgrp+3
    const int kb   = q << 3;            // frag k base
    const int b0   = blockIdx.x * ROWS;
    const int rowx = c & 7;             // clamped batch row for x/A loads
    const int arow = tid >> 4, acol = tid & 15;

    // ---------------- weights -> registers (hi/lo split) ----------------
    s8v B1h0, B1h1, B1l0, B1l1, B1a0, B1a1, B2h0, B2h1, B2l0, B2l1;
    s8v C1h0, C1h1, C1l0, C1l1, C2h0, C2h1, C2l0, C2l1;
    #pragma unroll
    for (int i = 0; i < 8; ++i) {
        const int k0 = kb + i, k1 = 32 + kb + i;
        float v;
        unsigned short h;
        v = Wp1[k0 * 64 + n]; h = f2bf(v); B1h0[i] = (short)h; B1l0[i] = (short)f2bf(v - bf2f(h));
        v = Wp1[k1 * 64 + n]; h = f2bf(v); B1h1[i] = (short)h; B1l1[i] = (short)f2bf(v - bf2f(h));
        v = Wp2[k0 * 64 + n]; h = f2bf(v); B2h0[i] = (short)h; B2l0[i] = (short)f2bf(v - bf2f(h));
        v = Wp2[k1 * 64 + n]; h = f2bf(v); B2h1[i] = (short)h; B2l1[i] = (short)f2bf(v - bf2f(h));
        const int ca = 64 + ((kb + i) & 15);   // a-rows of Wp1, stacked twice over K=32
        v = Wp1[ca * 64 + n]; h = f2bf(v); B1a0[i] = (short)h; B1a1[i] = (short)f2bf(v - bf2f(h));
        v = Wc1[k0 * 64 + n]; h = f2bf(v); C1h0[i] = (short)h; C1l0[i] = (short)f2bf(v - bf2f(h));
        v = Wc1[k1 * 64 + n]; h = f2bf(v); C1h1[i] = (short)h; C1l1[i] = (short)f2bf(v - bf2f(h));
        v = Wc2[k0 * 64 + n]; h = f2bf(v); C2h0[i] = (short)h; C2l0[i] = (short)f2bf(v - bf2f(h));
        v = Wc2[k1 * 64 + n]; h = f2bf(v); C2h1[i] = (short)h; C2l1[i] = (short)f2bf(v - bf2f(h));
    }
    const float b1 = bp1[n], b2 = bp2[n], cb1 = bc1[n], cb2 = bc2[n];

    // ---------------- zero LDS (keeps garbage rows finite) ----------------
    for (int i = tid; i < 1344; i += 256) reinterpret_cast<int*>(ha)[i]  = 0;
    for (int i = tid; i < 1216; i += 256) reinterpret_cast<int*>(t1s)[i] = 0;
    for (int i = tid; i < 1216; i += 256) reinterpret_cast<int*>(t1c)[i] = 0;
    __syncthreads();

    // ---------------- stage h0 (rows 0..7) and a[0] ----------------
    for (int idx = tid; idx < ROWS * 64; idx += 256) {
        const int row = idx >> 6, cc = idx & 63;
        float v = h0[(b0 + row) * 64 + cc];
        unsigned short h = f2bf(v);
        ha[row * 168 + cc]      = (short)h;
        ha[row * 168 + 64 + cc] = (short)f2bf(v - bf2f(h));
    }
    if (arow < ROWS) {
        float v = a[(long)(b0 + arow) * ACT + acol];
        unsigned short h = f2bf(v);
        ha[arow * 168 + 128 + acol] = (short)h;
        ha[arow * 168 + 144 + acol] = (short)f2bf(v - bf2f(h));
    }
    __syncthreads();

    // ---------------- prologue: z1[0] via capture layers ----------------
    float z1A[4], z1B[4];
    {
        const float* xr = x + (long)(b0 + rowx) * 64;
        float4 pa = *reinterpret_cast<const float4*>(xr + kb);
        float4 pb = *reinterpret_cast<const float4*>(xr + kb + 4);
        float4 pc = *reinterpret_cast<const float4*>(xr + 32 + kb);
        float4 pd = *reinterpret_cast<const float4*>(xr + 32 + kb + 4);
        s8v cf0, cf1, cf2, cf3;
        split8(pa, pb, cf0, cf2);
        split8(pc, pd, cf1, cf3);
        f4v u0 = {cb1, cb1, cb1, cb1};
        f4v u1 = {0.f, 0.f, 0.f, 0.f}, u2 = u1, u3 = u1;
        u0 = MFMA16(cf0, C1h0, u0); u1 = MFMA16(cf1, C1h1, u1);
        u2 = MFMA16(cf2, C1h0, u2); u3 = MFMA16(cf3, C1h1, u3);
        u0 = MFMA16(cf0, C1l0, u0); u1 = MFMA16(cf1, C1l1, u1);
        #pragma unroll
        for (int r = 0; r < 4; ++r) {
            float tv = ftanh((u0[r] + u1[r]) + (u2[r] + u3[r]));
            unsigned short h = f2bf(tv);
            t1c[(rgrp + r) * 152 + n]      = (short)h;
            t1c[(rgrp + r) * 152 + 64 + n] = (short)f2bf(tv - bf2f(h));
        }
        __syncthreads();
        const short* tcr = &t1c[c * 152];
        s8v cq0 = *reinterpret_cast<const s8v*>(tcr + kb);
        s8v cq1 = *reinterpret_cast<const s8v*>(tcr + 32 + kb);
        s8v cq2 = *reinterpret_cast<const s8v*>(tcr + 64 + kb);
        s8v cq3 = *reinterpret_cast<const s8v*>(tcr + 96 + kb);
        f4v d0 = {cb2, cb2, cb2, cb2};
        f4v d1 = {0.f, 0.f, 0.f, 0.f}, d2 = d1, d3 = d1;
        d0 = MFMA16(cq0, C2h0, d0); d1 = MFMA16(cq1, C2h1, d1);
        d2 = MFMA16(cq2, C2h0, d2); d3 = MFMA16(cq3, C2h1, d3);
        d0 = MFMA16(cq0, C2l0, d0); d1 = MFMA16(cq1, C2l1, d1);
        #pragma unroll
        for (int r = 0; r < 4; ++r) {
            z1A[r] = ftanh((d0[r] + d1[r]) + (d2[r] + d3[r]));
            if (rgrp + r < ROWS)
                capt[(long)(b0 + rgrp + r) * 64 + n] = z1A[r];
        }
    }

    // ---------------- pipeline registers ----------------
    float4 xa0, xa1, xa2, xa3, xb0, xb1, xb2, xb3;
    {
        const float* xr = x + ((long)1 * BATCH + b0 + rowx) * 64;
        xa0 = *reinterpret_cast<const float4*>(xr + kb);
        xa1 = *reinterpret_cast<const float4*>(xr + kb + 4);
        xa2 = *reinterpret_cast<const float4*>(xr + 32 + kb);
        xa3 = *reinterpret_cast<const float4*>(xr + 32 + kb + 4);
    }
    float gA[4], gB[4];
    #pragma unroll
    for (int r = 0; r < 4; ++r) gA[r] = g[b0 + ((rgrp + r) & 7)];
    float aA = a[((long)1 * BATCH + b0 + (arow & 7)) * ACT + acol];
    float aB = 0.f;
    float hlast[4];
    __syncthreads();

#define RSTEP(tt, GC, GN, AC, AN, Z1C, Z1N, XA0, XA1, XA2, XA3, XN0, XN1, XN2, XN3) do { \
    const int _t   = (tt);                                                            \
    const int _tp1 = (_t + 1 < T_STEPS) ? _t + 1 : T_STEPS - 1;                       \
    const int _tp2 = (_t + 2 < T_STEPS) ? _t + 2 : T_STEPS - 1;                       \
    /* ---- phase 1 ---- */                                                           \
    s8v cf0, cf1, cf2, cf3;   /* x[t+1] frags */                                      \
    split8(XA0, XA1, cf0, cf2);                                                       \
    split8(XA2, XA3, cf1, cf3);                                                       \
    {   const float* xr = x + ((long)_tp2 * BATCH + b0 + rowx) * 64;                  \
        XN0 = *reinterpret_cast<const float4*>(xr + kb);                              \
        XN1 = *reinterpret_cast<const float4*>(xr + kb + 4);                          \
        XN2 = *reinterpret_cast<const float4*>(xr + 32 + kb);                         \
        XN3 = *reinterpret_cast<const float4*>(xr + 32 + kb + 4); }                   \
    _Pragma("unroll")                                                                 \
    for (int r = 0; r < 4; ++r)                                                       \
        GN[r] = g[(long)_tp1 * BATCH + b0 + ((rgrp + r) & 7)];                        \
    AN = a[((long)_tp2 * BATCH + b0 + (arow & 7)) * ACT + acol];                      \
    const short* har = &ha[c * 168];                                                  \
    s8v af0 = *reinterpret_cast<const s8v*>(har + kb);                                \
    s8v af1 = *reinterpret_cast<const s8v*>(har + 32 + kb);                           \
    s8v af2 = *reinterpret_cast<const s8v*>(har + 64 + kb);                           \
    s8v af3 = *reinterpret_cast<const s8v*>(har + 96 + kb);                           \
    s8v afa = *reinterpret_cast<const s8v*>(har + 128 + kb);                          \
    f4v p0 = {b1, b1, b1, b1};                                                        \
    f4v p1 = {0.f, 0.f, 0.f, 0.f}, p2 = p1, p3 = p1;                                  \
    p0 = MFMA16(af0, B1h0, p0); p1 = MFMA16(af1, B1h1, p1);                           \
    p2 = MFMA16(af2, B1h0, p2); p3 = MFMA16(af3, B1h1, p3);                           \
    p0 = MFMA16(af0, B1l0, p0); p1 = MFMA16(af1, B1l1, p1);                           \
    p2 = MFMA16(afa, B1a0, p2); p3 = MFMA16(afa, B1a1, p3);                           \
    f4v u0 = {cb1, cb1, cb1, cb1};                                                    \
    f4v u1 = {0.f, 0.f, 0.f, 0.f}, u2 = u1, u3 = u1;                                  \
    u0 = MFMA16(cf0, C1h0, u0); u1 = MFMA16(cf1, C1h1, u1);                           \
    u2 = MFMA16(cf2, C1h0, u2); u3 = MFMA16(cf3, C1h1, u3);                           \
    u0 = MFMA16(cf0, C1l0, u0); u1 = MFMA16(cf1, C1l1, u1);                           \
    _Pragma("unroll")                                                                 \
    for (int r = 0; r < 4; ++r) {                                                     \
        float tv = ftanh((p0[r] + p1[r]) + (p2[r] + p3[r]));                          \
        unsigned short h = f2bf(tv);                                                  \
        t1s[(rgrp + r) * 152 + n]      = (short)h;                                    \
        t1s[(rgrp + r) * 152 + 64 + n] = (short)f2bf(tv - bf2f(h));                   \
        float cv = ftanh((u0[r] + u1[r]) + (u2[r] + u3[r]));                          \
        unsigned short hc = f2bf(cv);                                                 \
        t1c[(rgrp + r) * 152 + n]      = (short)hc;                                   \
        t1c[(rgrp + r) * 152 + 64 + n] = (short)f2bf(cv - bf2f(hc));                  \
    }                                                                                 \
    BAR();                                                                            \
    /* ---- phase 2 ---- */                                                           \
    const short* t1r = &t1s[c * 152];                                                 \
    s8v bq0 = *reinterpret_cast<const s8v*>(t1r + kb);                                \
    s8v bq1 = *reinterpret_cast<const s8v*>(t1r + 32 + kb);                           \
    s8v bq2 = *reinterpret_cast<const s8v*>(t1r + 64 + kb);                           \
    s8v bq3 = *reinterpret_cast<const s8v*>(t1r + 96 + kb);                           \
    const short* tcr = &t1c[c * 152];                                                 \
    s8v cq0 = *reinterpret_cast<const s8v*>(tcr + kb);                                \
    s8v cq1 = *reinterpret_cast<const s8v*>(tcr + 32 + kb);                           \
    s8v cq2 = *reinterpret_cast<const s8v*>(tcr + 64 + kb);                           \
    s8v cq3 = *reinterpret_cast<const s8v*>(tcr + 96 + kb);                           \
    f4v c0 = {b2, b2, b2, b2};                                                        \
    f4v c1 = {0.f, 0.f, 0.f, 0.f}, c2 = c1, c3 = c1;                                  \
    c0 = MFMA16(bq0, B2h0, c0); c1 = MFMA16(bq1, B2h1, c1);                           \
    c2 = MFMA16(bq2, B2h0, c2); c3 = MFMA16(bq3, B2h1, c3);                           \
    c0 = MFMA16(bq0, B2l0, c0); c1 = MFMA16(bq1, B2l1, c1);                           \
    f4v d0 = {cb2, cb2, cb2, cb2};                                                    \
    f4v d1 = {0.f, 0.f, 0.f, 0.f}, d2 = d1, d3 = d1;                                  \
    d0 = MFMA16(cq0, C2h0, d0); d1 = MFMA16(cq1, C2h1, d1);                           \
    d2 = MFMA16(cq2, C2h0, d2); d3 = MFMA16(cq3, C2h1, d3);                           \
    d0 = MFMA16(cq0, C2l0, d0); d1 = MFMA16(cq1, C2l1, d1);                           \
    _Pragma("unroll")                                                                 \
    for (int r = 0; r < 4; ++r) {                                                     \
        float z2 = ftanh((c0[r] + c1[r]) + (c2[r] + c3[r]));                          \
        float hv = fmaf(GC[r], z2 - Z1C[r], Z1C[r]);                                  \
        hlast[r] = hv;                                                                \
        if (rgrp + r < ROWS)                                                          \
            outs[((long)_t * BATCH + b0 + rgrp + r) * 64 + n] = hv;                   \
        unsigned short h = f2bf(hv);                                                  \
        ha[(rgrp + r) * 168 + n]      = (short)h;                                     \
        ha[(rgrp + r) * 168 + 64 + n] = (short)f2bf(hv - bf2f(h));                    \
        float z1v = ftanh((d0[r] + d1[r]) + (d2[r] + d3[r]));                         \
        Z1N[r] = z1v;                                                                 \
        if (rgrp + r < ROWS)                                                          \
            capt[((long)_tp1 * BATCH + b0 + rgrp + r) * 64 + n] = z1v;                \
    }                                                                                 \
    if (arow < ROWS) {                                                                \
        unsigned short h = f2bf(AC);                                                  \
        ha[arow * 168 + 128 + acol] = (short)h;                                       \
        ha[arow * 168 + 144 + acol] = (short)f2bf(AC - bf2f(h));                      \
    }                                                                                 \
    BAR();                                                                            \
} while (0)

    for (int t = 0; t < T_STEPS; t += 2) {
        RSTEP(t,     gA, gB, aA, aB, z1A, z1B, xa0, xa1, xa2, xa3, xb0, xb1, xb2, xb3);
        RSTEP(t + 1, gB, gA, aB, aA, z1B, z1A, xb0, xb1, xb2, xb3, xa0, xa1, xa2, xa3);
    }
#undef RSTEP

    #pragma unroll
    for (int r = 0; r < 4; ++r)
        if (rgrp + r < ROWS)
            hfin[(b0 + rgrp + r) * 64 + n] = hlast[r];
}

extern "C" void kernel_launch(void* const* d_in, const int* in_sizes, int n_in,
                              void* d_out, int out_size, void* d_ws, size_t ws_size,
                              hipStream_t stream) {
    const float* x   = (const float*)d_in[0];
    const float* h0  = (const float*)d_in[1];
    const float* g   = (const float*)d_in[2];
    const float* a   = (const float*)d_in[3];
    const float* Wc1 = (const float*)d_in[4];
    const float* bc1 = (const float*)d_in[5];
    const float* Wc2 = (const float*)d_in[6];
    const float* bc2 = (const float*)d_in[7];
    const float* Wp1 = (const float*)d_in[8];
    const float* bp1 = (const float*)d_in[9];
    const float* Wp2 = (const float*)d_in[10];
    const float* bp2 = (const float*)d_in[11];

    float* outs = (float*)d_out;
    float* hfin = outs + (long)T_STEPS * BATCH * HDIM;
    float* capt = hfin + (long)BATCH * HDIM;

    fused_cell<<<BATCH / ROWS, 256, 0, stream>>>(
        x, h0, g, a, Wc1, bc1, Wc2, bc2, Wp1, bp1, Wp2, bp2, outs, hfin, capt);
}

// Round 5
// 591.292 us; speedup vs baseline: 1.7832x; 1.7832x over previous
//
#include <hip/hip_runtime.h>
#include <hip/hip_bf16.h>

#define T_STEPS 512
#define BATCH   4096
#define ACT     16
#define HDIM    64
#define HA_S    168   // ha row stride (shorts): [h_hi 0..63 | h_lo 64..127 | a_hi 128..143 | a_lo 144..159]
#define T1_S    168   // t1/xs row stride (shorts): [hi 0..63 | lo 64..127]
#define Z1_S    66    // z1 handoff row stride (floats)

typedef short s8v __attribute__((ext_vector_type(8)));   // 8 bf16 MFMA A/B frag
typedef float f4v __attribute__((ext_vector_type(4)));   // MFMA C/D frag

#define MFMA16(A, B, C) __builtin_amdgcn_mfma_f32_16x16x32_bf16((A), (B), (C), 0, 0, 0)

// packed f32->bf16 (RNE), 2 values per instruction
__device__ __forceinline__ unsigned pkbf(float a, float b) {
    unsigned r;
    asm("v_cvt_pk_bf16_f32 %0, %1, %2" : "=v"(r) : "v"(a), "v"(b));
    return r;   // low16 = bf16(a), high16 = bf16(b)
}
__device__ __forceinline__ float lo16f(unsigned p) { return __builtin_bit_cast(float, p << 16); }
__device__ __forceinline__ float hi16f(unsigned p) { return __builtin_bit_cast(float, p & 0xFFFF0000u); }

// scalar versions for prologue weight prep (off critical path)
__device__ __forceinline__ unsigned short f2bf(float f) {
    unsigned u = __builtin_bit_cast(unsigned, f);
    u += 0x7FFFu + ((u >> 16) & 1u);
    return (unsigned short)(u >> 16);
}
__device__ __forceinline__ float bf2f(unsigned short b) {
    return __builtin_bit_cast(float, ((unsigned)b) << 16);
}

// tanh(x) = 1 - 2/(e^{2x}+1): exact at +-inf limits, no abs/copysign needed
__device__ __forceinline__ float ftanh(float x) {
    float e = __expf(2.0f * x);
    return 1.0f - 2.0f * __builtin_amdgcn_rcpf(e + 1.0f);
}

// raw barrier: drain LDS only; global loads/stores stay in flight across it
#define BAR() do { \
    asm volatile("s_waitcnt lgkmcnt(0)" ::: "memory"); \
    __builtin_amdgcn_s_barrier(); \
    asm volatile("" ::: "memory"); \
} while (0)

// stage 4 consecutive x floats as hi/lo bf16 planes (2x b64 LDS writes)
__device__ __forceinline__ void stage_x(short* xsb, int row, int col, float4 v) {
    unsigned h0 = pkbf(v.x, v.y), h1 = pkbf(v.z, v.w);
    float r0 = v.x - lo16f(h0), r1 = v.y - hi16f(h0);
    float r2 = v.z - lo16f(h1), r3 = v.w - hi16f(h1);
    unsigned l0 = pkbf(r0, r1), l1 = pkbf(r2, r3);
    uint2 hh; hh.x = h0; hh.y = h1;
    uint2 ll; ll.x = l0; ll.y = l1;
    *reinterpret_cast<uint2*>(&xsb[row * T1_S + col])      = hh;
    *reinterpret_cast<uint2*>(&xsb[row * T1_S + 64 + col]) = ll;
}

// capture layer 1: xs frags -> 6 MFMA -> tanh -> t1c (hi/lo)
__device__ __forceinline__ void cap_l1(const short* xsb, short* t1cb, int c, int kb, int rg, int n,
                                       s8v Wh0, s8v Wh1, s8v Wl0, s8v Wl1, float bias) {
    const short* xr_ = xsb + c * T1_S;
    s8v x0 = *(const s8v*)(xr_ + kb);
    s8v x1 = *(const s8v*)(xr_ + 32 + kb);
    s8v x2 = *(const s8v*)(xr_ + 64 + kb);
    s8v x3 = *(const s8v*)(xr_ + 96 + kb);
    f4v u0 = {bias, bias, bias, bias};
    f4v u1 = {0.f, 0.f, 0.f, 0.f}, u2 = u1, u3 = u1;
    u0 = MFMA16(x0, Wh0, u0); u1 = MFMA16(x1, Wh1, u1);
    u2 = MFMA16(x2, Wh0, u2); u3 = MFMA16(x3, Wh1, u3);
    u0 = MFMA16(x0, Wl0, u0); u1 = MFMA16(x1, Wl1, u1);
    #pragma unroll
    for (int r = 0; r < 4; ++r) {
        float tv = ftanh((u0[r] + u1[r]) + (u2[r] + u3[r]));
        unsigned ph = pkbf(tv, tv);
        float rr = tv - lo16f(ph);
        unsigned pl = pkbf(rr, rr);
        t1cb[(rg + r) * T1_S + n]      = (short)(ph & 0xFFFFu);
        t1cb[(rg + r) * T1_S + 64 + n] = (short)(pl & 0xFFFFu);
    }
}

// capture layer 2: t1c frags -> 6 MFMA -> tanh -> z1 values (f32)
__device__ __forceinline__ f4v cap_l2(const short* t1cb, int c, int kb,
                                      s8v Wh0, s8v Wh1, s8v Wl0, s8v Wl1, float bias) {
    const short* tr_ = t1cb + c * T1_S;
    s8v q0 = *(const s8v*)(tr_ + kb);
    s8v q1 = *(const s8v*)(tr_ + 32 + kb);
    s8v q2 = *(const s8v*)(tr_ + 64 + kb);
    s8v q3 = *(const s8v*)(tr_ + 96 + kb);
    f4v d0 = {bias, bias, bias, bias};
    f4v d1 = {0.f, 0.f, 0.f, 0.f}, d2 = d1, d3 = d1;
    d0 = MFMA16(q0, Wh0, d0); d1 = MFMA16(q1, Wh1, d1);
    d2 = MFMA16(q2, Wh0, d2); d3 = MFMA16(q3, Wh1, d3);
    d0 = MFMA16(q0, Wl0, d0); d1 = MFMA16(q1, Wl1, d1);
    f4v out;
    #pragma unroll
    for (int r = 0; r < 4; ++r)
        out[r] = ftanh((d0[r] + d1[r]) + (d2[r] + d3[r]));
    return out;
}

// 8 waves: waves 0-3 = recurrence chain (setprio 1), waves 4-7 = capture of z1[t+1].
// z1 handoff in LDS (double-buffered), x staged once per block in LDS.
__global__ __launch_bounds__(512, 2) void fused_cell(
    const float* __restrict__ x,  const float* __restrict__ h0,
    const float* __restrict__ g,  const float* __restrict__ a,
    const float* __restrict__ Wc1, const float* __restrict__ bc1,
    const float* __restrict__ Wc2, const float* __restrict__ bc2,
    const float* __restrict__ Wp1, const float* __restrict__ bp1,
    const float* __restrict__ Wp2, const float* __restrict__ bp2,
    float* __restrict__ outs, float* __restrict__ hfin, float* __restrict__ capt)
{
    __shared__ short ha [16 * HA_S];
    __shared__ short t1s[16 * T1_S];
    __shared__ short t1c[16 * T1_S];
    __shared__ short xs [16 * T1_S];
    __shared__ float z1b[2][16 * Z1_S];

    const int tid = threadIdx.x;
    const int wv  = tid >> 6;
    const bool cap = wv >= 4;
    const int w   = wv & 3;
    const int l   = tid & 63;
    const int c   = l & 15;            // A-frag row / D col
    const int q   = l >> 4;            // k-group / D row-group
    const int n   = (w << 4) | c;      // output channel
    const int rg  = q << 2;            // D rows rg..rg+3
    const int kb  = q << 3;            // frag k base
    const int b0  = blockIdx.x << 4;
    const int i2  = tid & 255;         // role-local lane
    const int xrow = i2 >> 4;          // staging row 0..15
    const int xcol = (i2 & 15) << 2;   // x staging col (floats)
    const int acol = i2 & 15;

    // ---- weights -> registers (hi/lo split); roles share register names ----
    s8v F1h0, F1h1, F1l0, F1l1, Fa0, Fa1, F2h0, F2h1, F2l0, F2l1;
    {
        const float* W1 = cap ? Wc1 : Wp1;
        const float* W2 = cap ? Wc2 : Wp2;
        #pragma unroll
        for (int i = 0; i < 8; ++i) {
            const int k0 = kb + i, k1 = 32 + kb + i;
            float v; unsigned short h;
            v = W1[k0 * 64 + n]; h = f2bf(v); F1h0[i] = (short)h; F1l0[i] = (short)f2bf(v - bf2f(h));
            v = W1[k1 * 64 + n]; h = f2bf(v); F1h1[i] = (short)h; F1l1[i] = (short)f2bf(v - bf2f(h));
            v = W2[k0 * 64 + n]; h = f2bf(v); F2h0[i] = (short)h; F2l0[i] = (short)f2bf(v - bf2f(h));
            v = W2[k1 * 64 + n]; h = f2bf(v); F2h1[i] = (short)h; F2l1[i] = (short)f2bf(v - bf2f(h));
        }
        if (!cap) {
            #pragma unroll
            for (int i = 0; i < 8; ++i) {
                const int ca_ = 64 + ((kb + i) & 15);  // a-rows of Wp1, K-space sums hi+lo of a
                float v = Wp1[ca_ * 64 + n]; unsigned short h = f2bf(v);
                Fa0[i] = (short)h; Fa1[i] = (short)f2bf(v - bf2f(h));
            }
        }
    }
    const float bzA = cap ? bc1[n] : bp1[n];
    const float bzB = cap ? bc2[n] : bp2[n];

    // ---- stage h0 (hi/lo) ----
    #pragma unroll
    for (int j = 0; j < 2; ++j) {
        int id = tid + j * 512;
        int row = id >> 6, cc = id & 63;
        float v = h0[(b0 + row) * 64 + cc];
        unsigned ph = pkbf(v, v);
        float rr = v - lo16f(ph);
        unsigned pl = pkbf(rr, rr);
        ha[row * HA_S + cc]      = (short)(ph & 0xFFFFu);
        ha[row * HA_S + 64 + cc] = (short)(pl & 0xFFFFu);
    }
    if (cap) {  // a[0]
        float v = a[(long)(b0 + xrow) * ACT + acol];
        unsigned ph = pkbf(v, v);
        float rr = v - lo16f(ph);
        unsigned pl = pkbf(rr, rr);
        ha[xrow * HA_S + 128 + acol] = (short)(ph & 0xFFFFu);
        ha[xrow * HA_S + 144 + acol] = (short)(pl & 0xFFFFu);
    }
    float4 xp0;
    if (cap) xp0 = *(const float4*)&x[(long)(b0 + xrow) * 64 + xcol];
    __syncthreads();

    // ---- prologue: z1[0] ----
    if (cap) stage_x(xs, xrow, xcol, xp0);          // xs <- x[0]
    __syncthreads();
    if (cap) cap_l1(xs, t1c, c, kb, rg, n, F1h0, F1h1, F1l0, F1l1, bzA);
    __syncthreads();

    float4 XC, XN;
    float  aC = 0.f, aN = 0.f;
    float  gC[4], gN[4];
    float  hl[4] = {0.f, 0.f, 0.f, 0.f};
    if (cap) {
        f4v z1o = cap_l2(t1c, c, kb, F2h0, F2h1, F2l0, F2l1, bzB);
        #pragma unroll
        for (int r = 0; r < 4; ++r) {
            z1b[0][(rg + r) * Z1_S + n] = z1o[r];
            capt[(long)(b0 + rg + r) * 64 + n] = z1o[r];
        }
        float4 x1v = *(const float4*)&x[((long)1 * BATCH + b0 + xrow) * 64 + xcol];
        stage_x(xs, xrow, xcol, x1v);               // xs <- x[1]
        XC = *(const float4*)&x[((long)2 * BATCH + b0 + xrow) * 64 + xcol];   // x[2]
        aC = a[((long)1 * BATCH + b0 + xrow) * ACT + acol];                   // a[1]
    } else {
        #pragma unroll
        for (int r = 0; r < 4; ++r) gC[r] = g[b0 + rg + r];                   // g[0]
        __builtin_amdgcn_s_setprio(1);              // recur chain = critical path
    }
    __syncthreads();

#define STEP(tt, PAR, GCv, GNv, ACv, ANv, XCv, XNv) {                           \
    const int t_  = (tt);                                                       \
    const int tp1 = (t_ + 1 < T_STEPS) ? t_ + 1 : T_STEPS - 1;                  \
    const int tp2 = (t_ + 2 < T_STEPS) ? t_ + 2 : T_STEPS - 1;                  \
    const int tp3 = (t_ + 3 < T_STEPS) ? t_ + 3 : T_STEPS - 1;                  \
    /* ---------------- phase 1 ---------------- */                             \
    if (!cap) {                                                                 \
        _Pragma("unroll")                                                       \
        for (int r = 0; r < 4; ++r)                                             \
            GNv[r] = g[(long)tp1 * BATCH + b0 + rg + r];                        \
        const short* har = &ha[c * HA_S];                                       \
        s8v af0 = *(const s8v*)(har + kb);                                      \
        s8v af1 = *(const s8v*)(har + 32 + kb);                                 \
        s8v af2 = *(const s8v*)(har + 64 + kb);                                 \
        s8v af3 = *(const s8v*)(har + 96 + kb);                                 \
        s8v afa = *(const s8v*)(har + 128 + kb);                                \
        f4v p0 = {bzA, bzA, bzA, bzA};                                          \
        f4v p1 = {0.f, 0.f, 0.f, 0.f}, p2 = p1, p3 = p1;                        \
        p0 = MFMA16(af0, F1h0, p0); p1 = MFMA16(af1, F1h1, p1);                 \
        p2 = MFMA16(af2, F1h0, p2); p3 = MFMA16(af3, F1h1, p3);                 \
        p0 = MFMA16(af0, F1l0, p0); p1 = MFMA16(af1, F1l1, p1);                 \
        p2 = MFMA16(afa, Fa0,  p2); p3 = MFMA16(afa, Fa1,  p3);                 \
        _Pragma("unroll")                                                       \
        for (int r = 0; r < 4; ++r) {                                           \
            float tv = ftanh((p0[r] + p1[r]) + (p2[r] + p3[r]));                \
            unsigned ph = pkbf(tv, tv);                                         \
            float rr = tv - lo16f(ph);                                          \
            unsigned pl = pkbf(rr, rr);                                         \
            t1s[(rg + r) * T1_S + n]      = (short)(ph & 0xFFFFu);              \
            t1s[(rg + r) * T1_S + 64 + n] = (short)(pl & 0xFFFFu);              \
        }                                                                       \
    } else {                                                                    \
        XNv = *(const float4*)&x[((long)tp3 * BATCH + b0 + xrow) * 64 + xcol];  \
        ANv = a[((long)tp2 * BATCH + b0 + xrow) * ACT + acol];                  \
        cap_l1(xs, t1c, c, kb, rg, n, F1h0, F1h1, F1l0, F1l1, bzA);             \
    }                                                                           \
    BAR();                                                                      \
    /* ---------------- phase 2 ---------------- */                             \
    if (!cap) {                                                                 \
        const short* t1r = &t1s[c * T1_S];                                      \
        s8v bq0 = *(const s8v*)(t1r + kb);                                      \
        s8v bq1 = *(const s8v*)(t1r + 32 + kb);                                 \
        s8v bq2 = *(const s8v*)(t1r + 64 + kb);                                 \
        s8v bq3 = *(const s8v*)(t1r + 96 + kb);                                 \
        f4v c0 = {bzB, bzB, bzB, bzB};                                          \
        f4v c1 = {0.f, 0.f, 0.f, 0.f}, c2 = c1, c3 = c1;                        \
        c0 = MFMA16(bq0, F2h0, c0); c1 = MFMA16(bq1, F2h1, c1);                 \
        c2 = MFMA16(bq2, F2h0, c2); c3 = MFMA16(bq3, F2h1, c3);                 \
        c0 = MFMA16(bq0, F2l0, c0); c1 = MFMA16(bq1, F2l1, c1);                 \
        _Pragma("unroll")                                                       \
        for (int r = 0; r < 4; ++r) {                                           \
            float z1v = z1b[PAR][(rg + r) * Z1_S + n];                          \
            float z2  = ftanh((c0[r] + c1[r]) + (c2[r] + c3[r]));               \
            float hv  = fmaf(GCv[r], z2 - z1v, z1v);                            \
            hl[r] = hv;                                                         \
            outs[((long)t_ * BATCH + b0 + rg + r) * 64 + n] = hv;               \
            unsigned ph = pkbf(hv, hv);                                         \
            float rr = hv - lo16f(ph);                                          \
            unsigned pl = pkbf(rr, rr);                                         \
            ha[(rg + r) * HA_S + n]      = (short)(ph & 0xFFFFu);               \
            ha[(rg + r) * HA_S + 64 + n] = (short)(pl & 0xFFFFu);               \
        }                                                                       \
    } else {                                                                    \
        f4v z1o = cap_l2(t1c, c, kb, F2h0, F2h1, F2l0, F2l1, bzB);              \
        _Pragma("unroll")                                                       \
        for (int r = 0; r < 4; ++r) {                                           \
            z1b[PAR ^ 1][(rg + r) * Z1_S + n] = z1o[r];                         \
            if (t_ < T_STEPS - 1)                                               \
                capt[((long)(t_ + 1) * BATCH + b0 + rg + r) * 64 + n] = z1o[r]; \
        }                                                                       \
        stage_x(xs, xrow, xcol, XCv);               /* xs <- x[t+2] */          \
        {                                                                       \
            unsigned ph = pkbf(ACv, ACv);           /* ha.a <- a[t+1] */        \
            float rr = ACv - lo16f(ph);                                         \
            unsigned pl = pkbf(rr, rr);                                         \
            ha[xrow * HA_S + 128 + acol] = (short)(ph & 0xFFFFu);               \
            ha[xrow * HA_S + 144 + acol] = (short)(pl & 0xFFFFu);               \
        }                                                                       \
    }                                                                           \
    BAR();                                                                      \
}

    for (int t = 0; t < T_STEPS; t += 2) {
        STEP(t,     0, gC, gN, aC, aN, XC, XN);
        STEP(t + 1, 1, gN, gC, aN, aC, XN, XC);
    }
#undef STEP

    if (!cap) {
        #pragma unroll
        for (int r = 0; r < 4; ++r)
            hfin[(long)(b0 + rg + r) * 64 + n] = hl[r];
    }
}

extern "C" void kernel_launch(void* const* d_in, const int* in_sizes, int n_in,
                              void* d_out, int out_size, void* d_ws, size_t ws_size,
                              hipStream_t stream) {
    const float* x   = (const float*)d_in[0];
    const float* h0  = (const float*)d_in[1];
    const float* g   = (const float*)d_in[2];
    const float* a   = (const float*)d_in[3];
    const float* Wc1 = (const float*)d_in[4];
    const float* bc1 = (const float*)d_in[5];
    const float* Wc2 = (const float*)d_in[6];
    const float* bc2 = (const float*)d_in[7];
    const float* Wp1 = (const float*)d_in[8];
    const float* bp1 = (const float*)d_in[9];
    const float* Wp2 = (const float*)d_in[10];
    const float* bp2 = (const float*)d_in[11];

    float* outs = (float*)d_out;
    float* hfin = outs + (long)T_STEPS * BATCH * HDIM;
    float* capt = hfin + (long)BATCH * HDIM;

    fused_cell<<<BATCH / 16, 512, 0, stream>>>(
        x, h0, g, a, Wc1, bc1, Wc2, bc2, Wp1, bp1, Wp2, bp2, outs, hfin, capt);
}

// Round 6
// 581.196 us; speedup vs baseline: 1.8142x; 1.0174x over previous
//
#include <hip/hip_runtime.h>
#include <hip/hip_bf16.h>

#define T_STEPS 512
#define BATCH   4096
#define ACT     16
#define HDIM    64
#define HA_S    168   // ha row stride (shorts): [h_hi 0..63 | h_lo 64..127 | a_hi 128..143 | a_lo 144..159]
#define T1S_S   72    // t1 row stride (shorts): [hi 0..63 | pad] (144B: 16B-aligned, 2-way banks)
#define XS_S    136   // xs row stride (shorts): [hi 0..63 | lo 64..127 | pad] (272B: 16B-aligned)
#define Z1_S    66    // z1 handoff row stride (floats)

typedef short s8v __attribute__((ext_vector_type(8)));   // 8 bf16 MFMA A/B frag
typedef float f4v __attribute__((ext_vector_type(4)));   // MFMA C/D frag

#define MFMA16(A, B, C) __builtin_amdgcn_mfma_f32_16x16x32_bf16((A), (B), (C), 0, 0, 0)

// packed f32->bf16 (RNE), 2 values per instruction
__device__ __forceinline__ unsigned pkbf(float a, float b) {
    unsigned r;
    asm("v_cvt_pk_bf16_f32 %0, %1, %2" : "=v"(r) : "v"(a), "v"(b));
    return r;   // low16 = bf16(a), high16 = bf16(b)
}
__device__ __forceinline__ float lo16f(unsigned p) { return __builtin_bit_cast(float, p << 16); }
__device__ __forceinline__ float hi16f(unsigned p) { return __builtin_bit_cast(float, p & 0xFFFF0000u); }

// scalar versions (prologue weight prep only)
__device__ __forceinline__ unsigned short f2bf(float f) {
    unsigned u = __builtin_bit_cast(unsigned, f);
    u += 0x7FFFu + ((u >> 16) & 1u);
    return (unsigned short)(u >> 16);
}
__device__ __forceinline__ float bf2f(unsigned short b) {
    return __builtin_bit_cast(float, ((unsigned)b) << 16);
}

// tanh(x) = 1 - 2/(e^{2x}+1): exact at +-inf limits
__device__ __forceinline__ float ftanh(float x) {
    float e = __expf(2.0f * x);
    return fmaf(-2.0f, __builtin_amdgcn_rcpf(e + 1.0f), 1.0f);
}

// raw barrier: drain LDS only; global loads/stores stay in flight across it
#define BAR() do { \
    asm volatile("s_waitcnt lgkmcnt(0)" ::: "memory"); \
    __builtin_amdgcn_s_barrier(); \
    asm volatile("" ::: "memory"); \
} while (0)

// stage 4 consecutive x floats as hi/lo bf16 planes (2x b64 LDS writes)
__device__ __forceinline__ void stage_x(short* p, float4 v) {
    unsigned h0p = pkbf(v.x, v.y), h1p = pkbf(v.z, v.w);
    float r0 = v.x - lo16f(h0p), r1 = v.y - hi16f(h0p);
    float r2 = v.z - lo16f(h1p), r3 = v.w - hi16f(h1p);
    uint2 hh; hh.x = h0p; hh.y = h1p;
    uint2 ll; ll.x = pkbf(r0, r1); ll.y = pkbf(r2, r3);
    *reinterpret_cast<uint2*>(p)      = hh;
    *reinterpret_cast<uint2*>(p + 64) = ll;
}

// 8 waves: waves 0-3 recurrence (setprio 1), waves 4-7 capture of z1[t+1].
// All global streams via incrementally-advanced per-lane pointers.
__global__ __launch_bounds__(512, 2) void fused_cell(
    const float* __restrict__ x,  const float* __restrict__ h0,
    const float* __restrict__ g,  const float* __restrict__ a,
    const float* __restrict__ Wc1, const float* __restrict__ bc1,
    const float* __restrict__ Wc2, const float* __restrict__ bc2,
    const float* __restrict__ Wp1, const float* __restrict__ bp1,
    const float* __restrict__ Wp2, const float* __restrict__ bp2,
    float* __restrict__ outs, float* __restrict__ hfin, float* __restrict__ capt)
{
    __shared__ short ha [16 * HA_S];
    __shared__ short t1s[16 * T1S_S];
    __shared__ short t1c[16 * T1S_S];
    __shared__ short xs [16 * XS_S];
    __shared__ float z1b[2][16 * Z1_S];

    const int tid = threadIdx.x;
    const bool cap = tid >= 256;
    const int w   = (tid >> 6) & 3;
    const int l   = tid & 63;
    const int c   = l & 15;
    const int q   = l >> 4;
    const int n   = (w << 4) | c;
    const int rg  = q << 2;
    const int kb  = q << 3;
    const int b0  = blockIdx.x << 4;
    const int i2  = tid & 255;
    const int xrow = i2 >> 4;
    const int xcol = (i2 & 15) << 2;
    const int acol = i2 & 15;

    // ---- weights -> registers (role-shared names) ----
    s8v F1h0, F1h1, Fa0, F2h0, F2h1, F2l0, F2l1;
    {
        const float* W1 = cap ? Wc1 : Wp1;
        const float* W2 = cap ? Wc2 : Wp2;
        #pragma unroll
        for (int i = 0; i < 8; ++i) {
            const int k0 = kb + i, k1 = 32 + kb + i;
            F1h0[i] = (short)f2bf(W1[k0 * 64 + n]);
            F1h1[i] = (short)f2bf(W1[k1 * 64 + n]);
            float v2a = W2[k0 * 64 + n]; unsigned short h2a = f2bf(v2a);
            F2h0[i] = (short)h2a; F2l0[i] = (short)f2bf(v2a - bf2f(h2a));
            float v2b = W2[k1 * 64 + n]; unsigned short h2b = f2bf(v2b);
            F2h1[i] = (short)h2b; F2l1[i] = (short)f2bf(v2b - bf2f(h2b));
        }
        if (!cap) {
            #pragma unroll
            for (int i = 0; i < 8; ++i)
                Fa0[i] = (short)f2bf(Wp1[(64 + ((kb + i) & 15)) * 64 + n]);
        }
    }
    const float bz1 = cap ? bc1[n] : bp1[n];
    const float bz2 = cap ? bc2[n] : bp2[n];

    // ---- LDS base pointers (hoisted) ----
    const short* ha_rd  = &ha [c * HA_S];
    short*       ha_wr  = &ha [rg * HA_S + n];
    short*       ha_awr = &ha [xrow * HA_S + 128 + acol];
    const short* t1s_rd = &t1s[c * T1S_S];
    short*       t1s_wr = &t1s[rg * T1S_S + n];
    const short* t1c_rd = &t1c[c * T1S_S];
    short*       t1c_wr = &t1c[rg * T1S_S + n];
    const short* xs_rd  = &xs [c * XS_S];
    short*       xs_wr  = &xs [xrow * XS_S + xcol];
    const float* z1r0 = &z1b[0][rg * Z1_S + n];
    const float* z1r1 = &z1b[1][rg * Z1_S + n];
    float*       z1w0 = &z1b[0][rg * Z1_S + n];
    float*       z1w1 = &z1b[1][rg * Z1_S + n];

    // ---- stage h0 (hi/lo) + a[0] ----
    #pragma unroll
    for (int j = 0; j < 2; ++j) {
        int id = tid + j * 512;
        int row = id >> 6, cc = id & 63;
        float v = h0[(b0 + row) * 64 + cc];
        unsigned ph = pkbf(v, v);
        float rr = v - lo16f(ph);
        ha[row * HA_S + cc]      = (short)ph;
        ha[row * HA_S + 64 + cc] = (short)pkbf(rr, rr);
    }
    if (cap) {
        float v = a[(long)(b0 + xrow) * ACT + acol];
        unsigned ph = pkbf(v, v);
        float rr = v - lo16f(ph);
        ha_awr[0]  = (short)ph;
        ha_awr[16] = (short)pkbf(rr, rr);
    }
    __syncthreads();

    if (cap) {   // stage x[0]
        float4 v0 = *(const float4*)&x[(long)(b0 + xrow) * 64 + xcol];
        stage_x(xs_wr, v0);
    }
    __syncthreads();

    if (cap) {   // capture L1 for t=0
        s8v x0 = *(const s8v*)(xs_rd + kb);
        s8v x1 = *(const s8v*)(xs_rd + 32 + kb);
        s8v x2 = *(const s8v*)(xs_rd + 64 + kb);
        s8v x3 = *(const s8v*)(xs_rd + 96 + kb);
        f4v p0 = {bz1, bz1, bz1, bz1};
        f4v p1 = {0.f, 0.f, 0.f, 0.f}, p2 = p1, p3 = p1;
        p0 = MFMA16(x0, F1h0, p0); p1 = MFMA16(x1, F1h1, p1);
        p2 = MFMA16(x2, F1h0, p2); p3 = MFMA16(x3, F1h1, p3);
        #pragma unroll
        for (int r = 0; r < 4; ++r) {
            float tv = ftanh((p0[r] + p1[r]) + (p2[r] + p3[r]));
            t1c_wr[r * T1S_S] = (short)pkbf(tv, tv);
        }
    }
    __syncthreads();

    // ---- pipeline registers + stream pointers ----
    float4 XC, XN;
    float  aC = 0.f, aN = 0.f;
    float  gC4[4], gN4[4];
    float  hl[4] = {0.f, 0.f, 0.f, 0.f};
    const float *gp = g, *xp = x, *ap = a;
    float *outp = outs, *cp = capt;

    if (cap) {   // capture L2 for t=0 -> z1b[0] + capt[0]; stage x[1]; prime streams
        s8v q0_ = *(const s8v*)(t1c_rd + kb);
        s8v q1_ = *(const s8v*)(t1c_rd + 32 + kb);
        f4v d0 = {bz2, bz2, bz2, bz2};
        f4v d1 = {0.f, 0.f, 0.f, 0.f};
        d0 = MFMA16(q0_, F2h0, d0); d1 = MFMA16(q1_, F2h1, d1);
        d0 = MFMA16(q0_, F2l0, d0); d1 = MFMA16(q1_, F2l1, d1);
        #pragma unroll
        for (int r = 0; r < 4; ++r) {
            float zv = ftanh(d0[r] + d1[r]);
            z1w0[r * Z1_S] = zv;
            capt[(long)(b0 + rg + r) * 64 + n] = zv;
        }
        float4 x1v = *(const float4*)&x[((long)BATCH + b0 + xrow) * 64 + xcol];
        stage_x(xs_wr, x1v);                                  // xs <- x[1]
        XC = *(const float4*)&x[((long)2 * BATCH + b0 + xrow) * 64 + xcol];
        aC = a[((long)BATCH + b0 + xrow) * ACT + acol];
        xp = &x[((long)3 * BATCH + b0 + xrow) * 64 + xcol];
        ap = &a[((long)2 * BATCH + b0 + xrow) * ACT + acol];
        cp = &capt[((long)BATCH + b0 + rg) * 64 + n];
    } else {
        #pragma unroll
        for (int r = 0; r < 4; ++r) gC4[r] = g[b0 + rg + r];  // g[0]
        gp   = &g[(long)BATCH + b0 + rg];
        outp = &outs[(long)(b0 + rg) * 64 + n];
        __builtin_amdgcn_s_setprio(1);
    }
    __syncthreads();

#define STEP(tt, PAR, GCv, GNv, ACv, ANv, XCv, XNv) {                         \
    const int t_ = (tt);                                                      \
    /* ---------------- phase 1 ---------------- */                           \
    if (!cap) {                                                               \
        float4 gv = *(const float4*)gp;                                       \
        GNv[0] = gv.x; GNv[1] = gv.y; GNv[2] = gv.z; GNv[3] = gv.w;           \
        if (t_ + 2 < T_STEPS) gp += BATCH;                                    \
        s8v af0 = *(const s8v*)(ha_rd + kb);                                  \
        s8v af1 = *(const s8v*)(ha_rd + 32 + kb);                             \
        s8v af2 = *(const s8v*)(ha_rd + 64 + kb);                             \
        s8v af3 = *(const s8v*)(ha_rd + 96 + kb);                             \
        s8v afa = *(const s8v*)(ha_rd + 128 + kb);                            \
        f4v p0 = {bz1, bz1, bz1, bz1};                                        \
        f4v p1 = {0.f, 0.f, 0.f, 0.f}, p2 = p1, p3 = p1;                      \
        p0 = MFMA16(af0, F1h0, p0); p1 = MFMA16(af1, F1h1, p1);               \
        p2 = MFMA16(af2, F1h0, p2); p3 = MFMA16(af3, F1h1, p3);               \
        p2 = MFMA16(afa, Fa0,  p2);                                           \
        _Pragma("unroll")                                                     \
        for (int r = 0; r < 4; ++r) {                                         \
            float tv = ftanh((p0[r] + p1[r]) + (p2[r] + p3[r]));              \
            t1s_wr[r * T1S_S] = (short)pkbf(tv, tv);                          \
        }                                                                     \
    } else {                                                                  \
        XNv = *(const float4*)xp;                                             \
        if (t_ + 4 < T_STEPS) xp += (long)BATCH * 64;                         \
        ANv = *ap;                                                            \
        if (t_ + 3 < T_STEPS) ap += BATCH * ACT;                              \
        s8v x0 = *(const s8v*)(xs_rd + kb);                                   \
        s8v x1 = *(const s8v*)(xs_rd + 32 + kb);                              \
        s8v x2 = *(const s8v*)(xs_rd + 64 + kb);                              \
        s8v x3 = *(const s8v*)(xs_rd + 96 + kb);                              \
        f4v p0 = {bz1, bz1, bz1, bz1};                                        \
        f4v p1 = {0.f, 0.f, 0.f, 0.f}, p2 = p1, p3 = p1;                      \
        p0 = MFMA16(x0, F1h0, p0); p1 = MFMA16(x1, F1h1, p1);                 \
        p2 = MFMA16(x2, F1h0, p2); p3 = MFMA16(x3, F1h1, p3);                 \
        _Pragma("unroll")                                                     \
        for (int r = 0; r < 4; ++r) {                                         \
            float tv = ftanh((p0[r] + p1[r]) + (p2[r] + p3[r]));              \
            t1c_wr[r * T1S_S] = (short)pkbf(tv, tv);                          \
        }                                                                     \
    }                                                                         \
    BAR();                                                                    \
    /* ---------------- phase 2 ---------------- */                           \
    if (!cap) {                                                               \
        s8v bq0 = *(const s8v*)(t1s_rd + kb);                                 \
        s8v bq1 = *(const s8v*)(t1s_rd + 32 + kb);                            \
        f4v c0 = {bz2, bz2, bz2, bz2};                                        \
        f4v c1 = {0.f, 0.f, 0.f, 0.f};                                        \
        c0 = MFMA16(bq0, F2h0, c0); c1 = MFMA16(bq1, F2h1, c1);               \
        c0 = MFMA16(bq0, F2l0, c0); c1 = MFMA16(bq1, F2l1, c1);               \
        const float* zr = (PAR) ? z1r1 : z1r0;                                \
        _Pragma("unroll")                                                     \
        for (int r = 0; r < 4; ++r) {                                         \
            float z1v = zr[r * Z1_S];                                         \
            float z2  = ftanh(c0[r] + c1[r]);                                 \
            float hv  = fmaf(GCv[r], z2 - z1v, z1v);                          \
            hl[r] = hv;                                                       \
            outp[r * HDIM] = hv;                                              \
            unsigned ph = pkbf(hv, hv);                                       \
            float rr = hv - lo16f(ph);                                        \
            ha_wr[r * HA_S]      = (short)ph;                                 \
            ha_wr[r * HA_S + 64] = (short)pkbf(rr, rr);                       \
        }                                                                     \
        outp += (long)BATCH * HDIM;                                           \
    } else {                                                                  \
        s8v q0_ = *(const s8v*)(t1c_rd + kb);                                 \
        s8v q1_ = *(const s8v*)(t1c_rd + 32 + kb);                            \
        f4v d0 = {bz2, bz2, bz2, bz2};                                        \
        f4v d1 = {0.f, 0.f, 0.f, 0.f};                                        \
        d0 = MFMA16(q0_, F2h0, d0); d1 = MFMA16(q1_, F2h1, d1);               \
        d0 = MFMA16(q0_, F2l0, d0); d1 = MFMA16(q1_, F2l1, d1);               \
        float* zw = (PAR) ? z1w0 : z1w1;                                      \
        _Pragma("unroll")                                                     \
        for (int r = 0; r < 4; ++r) {                                         \
            float zv = ftanh(d0[r] + d1[r]);                                  \
            zw[r * Z1_S] = zv;                                                \
            if (t_ < T_STEPS - 1) cp[r * HDIM] = zv;                          \
        }                                                                     \
        cp += (long)BATCH * HDIM;                                             \
        stage_x(xs_wr, XCv);                   /* xs <- x[t+2] */             \
        unsigned ph = pkbf(ACv, ACv);          /* ha.a <- a[t+1] */           \
        float rr = ACv - lo16f(ph);                                           \
        ha_awr[0]  = (short)ph;                                               \
        ha_awr[16] = (short)pkbf(rr, rr);                                     \
    }                                                                         \
    BAR();                                                                    \
}

    for (int t = 0; t < T_STEPS; t += 2) {
        STEP(t,     0, gC4, gN4, aC, aN, XC, XN);
        STEP(t + 1, 1, gN4, gC4, aN, aC, XN, XC);
    }
#undef STEP

    if (!cap) {
        #pragma unroll
        for (int r = 0; r < 4; ++r)
            hfin[(long)(b0 + rg + r) * 64 + n] = hl[r];
    }
}

extern "C" void kernel_launch(void* const* d_in, const int* in_sizes, int n_in,
                              void* d_out, int out_size, void* d_ws, size_t ws_size,
                              hipStream_t stream) {
    const float* x   = (const float*)d_in[0];
    const float* h0  = (const float*)d_in[1];
    const float* g   = (const float*)d_in[2];
    const float* a   = (const float*)d_in[3];
    const float* Wc1 = (const float*)d_in[4];
    const float* bc1 = (const float*)d_in[5];
    const float* Wc2 = (const float*)d_in[6];
    const float* bc2 = (const float*)d_in[7];
    const float* Wp1 = (const float*)d_in[8];
    const float* bp1 = (const float*)d_in[9];
    const float* Wp2 = (const float*)d_in[10];
    const float* bp2 = (const float*)d_in[11];

    float* outs = (float*)d_out;
    float* hfin = outs + (long)T_STEPS * BATCH * HDIM;
    float* capt = hfin + (long)BATCH * HDIM;

    fused_cell<<<BATCH / 16, 512, 0, stream>>>(
        x, h0, g, a, Wc1, bc1, Wc2, bc2, Wp1, bp1, Wp2, bp2, outs, hfin, capt);
}